// Round 1
// baseline (89.118 us; speedup 1.0000x reference)
//
#include <hip/hip_runtime.h>

// lat [2048,2048] fp32 -> 131072 rows x D=32; centroids [1024,32] fp32.
// out = [lat * clamp(lf,1e-3,1e3)] ++ [1.25 * mean_{N,D}(min_k ||z-c_k||^2)]
#define D 32
#define K 1024
#define N_ROWS 131072
#define TOTAL_ELEMS 4194304
#define LOSS_SCALE (1.25f / 4194304.0f)

typedef __attribute__((ext_vector_type(8))) short short8;   // 8 bf16
typedef __attribute__((ext_vector_type(4))) float f32x4;

__device__ __forceinline__ unsigned short f2bf(float f) {
  unsigned u = __builtin_bit_cast(unsigned, f);
  unsigned r = u + 0x7FFFu + ((u >> 16) & 1u);   // RNE
  return (unsigned short)(r >> 16);
}

// ---- prep: centbf = bf16(-2c) in PERMUTED chunk order; cnormb4; loss=0 ----
// Permutation: chunk (f, c, q) -> index f*64 + q*16 + c, so that vq's lane l
// reads chunk  f*64 + l  == (cent = f*16 + (l&15), kchunk = l>>4).
// This makes the hot-loop ds_read_b128 64 consecutive 16B elements per wave
// (conflict-free) instead of the previous 8-way bank conflict.
__global__ __launch_bounds__(256) void prep_kernel(
    const float* __restrict__ cent, unsigned short* __restrict__ centbf,
    float4* __restrict__ cnormb4, float* __restrict__ loss_out) {
  int t = blockIdx.x * 256 + threadIdx.x;   // 0..4095 : one 8-elem chunk each
  if (t == 0) *loss_out = 0.0f;
  {
    int f = t >> 6;
    int rem = t & 63;
    int q = rem >> 4;          // k-chunk 0..3
    int c = rem & 15;          // cent-in-frag
    int k0 = f * 16 + c;       // centroid row
    const float* src = cent + k0 * D + q * 8;
    float4 u0 = ((const float4*)src)[0];
    float4 u1 = ((const float4*)src)[1];
    short8 ch;
    ch[0] = (short)f2bf(-2.0f * u0.x); ch[1] = (short)f2bf(-2.0f * u0.y);
    ch[2] = (short)f2bf(-2.0f * u0.z); ch[3] = (short)f2bf(-2.0f * u0.w);
    ch[4] = (short)f2bf(-2.0f * u1.x); ch[5] = (short)f2bf(-2.0f * u1.y);
    ch[6] = (short)f2bf(-2.0f * u1.z); ch[7] = (short)f2bf(-2.0f * u1.w);
    ((short8*)centbf)[t] = ch;            // coalesced 16B store
  }
  if (t < K) {
    const float* c = cent + t * D;
    float s0 = 0.f, s1 = 0.f, s2 = 0.f, s3 = 0.f;
#pragma unroll
    for (int d = 0; d < D; d += 4) {
      s0 = fmaf(c[d], c[d], s0);
      s1 = fmaf(c[d + 1], c[d + 1], s1);
      s2 = fmaf(c[d + 2], c[d + 2], s2);
      s3 = fmaf(c[d + 3], c[d + 3], s3);
    }
    float cn = (s0 + s1) + (s2 + s3);
    cnormb4[t] = make_float4(cn, cn, cn, cn);   // pre-broadcast for MFMA C
  }
}

// ---- vq: conflict-free B-read, 4 A-tiles (64 rows) per wave ---------------
// 256 thr (4 waves), grid 512, 80 KB LDS -> 2 blocks/CU (160 KB exactly).
// Per f-iter: 1 conflict-free ds_read_b128 (B) + 1 cn read feed 4 MFMAs
// (was 2 reads : 2 MFMAs with an 8-way-conflicted B read).
__global__ __launch_bounds__(256) void vq_kernel(
    const float* __restrict__ lat, const unsigned short* __restrict__ centbf,
    const float4* __restrict__ cnormb4, const float* __restrict__ lf_ptr,
    float* __restrict__ out, float* __restrict__ loss_out) {
  __shared__ short8 sB8[4096];   // 64 KB: permuted codebook, bf16(-2c)
  __shared__ f32x4 sCn4[1024];   // 16 KB: {cn,cn,cn,cn} per centroid
  const int tid = threadIdx.x;
  const int lane = tid & 63;
  const int wave = tid >> 6;     // 0..3
  const int quad = lane >> 4;
  const int col  = lane & 15;
  const int rowbase = blockIdx.x * 256 + wave * 64;   // 64 rows per wave

  // One-time stage of codebook + replicated cnorm (coalesced, 256 threads).
  {
    const short8* gB8 = (const short8*)centbf;   // 4096 chunks
#pragma unroll
    for (int j = 0; j < 16; ++j) sB8[j * 256 + tid] = gB8[j * 256 + tid];
    const uint4* g4 = (const uint4*)cnormb4;     // 1024 chunks
    uint4* s4 = (uint4*)sCn4;
#pragma unroll
    for (int j = 0; j < 4; ++j) s4[j * 256 + tid] = g4[j * 256 + tid];
  }

  // A-frags for 4 row-tiles + fused scale-store + fp32 ||z||^2 partial.
  float lf = fminf(fmaxf(lf_ptr[0], 0.001f), 1000.0f);
  short8 a[4];
  float zz = 0.0f;
#pragma unroll
  for (int t = 0; t < 4; ++t) {
    const float* p = lat + (size_t)(rowbase + t * 16 + col) * D + quad * 8;
    float4 u0 = ((const float4*)p)[0], u1 = ((const float4*)p)[1];
    a[t][0] = (short)f2bf(u0.x); a[t][1] = (short)f2bf(u0.y);
    a[t][2] = (short)f2bf(u0.z); a[t][3] = (short)f2bf(u0.w);
    a[t][4] = (short)f2bf(u1.x); a[t][5] = (short)f2bf(u1.y);
    a[t][6] = (short)f2bf(u1.z); a[t][7] = (short)f2bf(u1.w);
    float t0 = fmaf(u0.x, u0.x, fmaf(u0.y, u0.y, fmaf(u0.z, u0.z, u0.w * u0.w)));
    float t1 = fmaf(u1.x, u1.x, fmaf(u1.y, u1.y, fmaf(u1.z, u1.z, u1.w * u1.w)));
    zz += t0 + t1;
    float* o = out + (size_t)(rowbase + t * 16 + col) * D + quad * 8;
    float4 s0 = {u0.x * lf, u0.y * lf, u0.z * lf, u0.w * lf};
    float4 s1 = {u1.x * lf, u1.y * lf, u1.z * lf, u1.w * lf};
    ((float4*)o)[0] = s0;
    ((float4*)o)[1] = s1;
  }
  __syncthreads();

  const float INF = 3.4e38f;
  float m0[4] = {INF, INF, INF, INF};
  float m1[4] = {INF, INF, INF, INF};
  float m2[4] = {INF, INF, INF, INF};
  float m3[4] = {INF, INF, INF, INF};

#pragma unroll 4
  for (int f = 0; f < 64; ++f) {
    short8 b = sB8[f * 64 + lane];         // conflict-free: 64 contiguous 16B
    f32x4 c4 = sCn4[f * 16 + col];         // 16 addrs x4 broadcast (free)
    f32x4 d0 = __builtin_amdgcn_mfma_f32_16x16x32_bf16(a[0], b, c4, 0, 0, 0);
    f32x4 d1 = __builtin_amdgcn_mfma_f32_16x16x32_bf16(a[1], b, c4, 0, 0, 0);
    f32x4 d2 = __builtin_amdgcn_mfma_f32_16x16x32_bf16(a[2], b, c4, 0, 0, 0);
    f32x4 d3 = __builtin_amdgcn_mfma_f32_16x16x32_bf16(a[3], b, c4, 0, 0, 0);
#pragma unroll
    for (int r = 0; r < 4; ++r) {
      m0[r] = fminf(m0[r], d0[r]);   // score = dot + cn came out of the MFMA
      m1[r] = fminf(m1[r], d1[r]);
      m2[r] = fminf(m2[r], d2[r]);
      m3[r] = fminf(m3[r], d3[r]);
    }
  }

  // Min across the 16 cols of each quad-group (lane bits 0..3). One-time.
#pragma unroll
  for (int off = 1; off < 16; off <<= 1) {
#pragma unroll
    for (int r = 0; r < 4; ++r) {
      m0[r] = fminf(m0[r], __shfl_xor(m0[r], off));
      m1[r] = fminf(m1[r], __shfl_xor(m1[r], off));
      m2[r] = fminf(m2[r], __shfl_xor(m2[r], off));
      m3[r] = fminf(m3[r], __shfl_xor(m3[r], off));
    }
  }

  // Row-min sums: quad's 4 rows x 4 tiles, then quads via bits 4,5.
  float s = (((m0[0] + m0[1]) + (m0[2] + m0[3])) +
             ((m1[0] + m1[1]) + (m1[2] + m1[3]))) +
            (((m2[0] + m2[1]) + (m2[2] + m2[3])) +
             ((m3[0] + m3[1]) + (m3[2] + m3[3])));
  s += __shfl_xor(s, 16);
  s += __shfl_xor(s, 32);

  // Wave sum of ||z||^2 partials (every element exactly once).
  zz += __shfl_xor(zz, 1);
  zz += __shfl_xor(zz, 2);
  zz += __shfl_xor(zz, 4);
  zz += __shfl_xor(zz, 8);
  zz += __shfl_xor(zz, 16);
  zz += __shfl_xor(zz, 32);

  float total = s + zz;
  __syncthreads();                  // all waves done reading sB8/sCn4
  float* wsum = (float*)sB8;        // reuse dead codebook LDS
  if (lane == 0) wsum[wave] = total;
  __syncthreads();
  if (tid == 0) {
    float blk = (wsum[0] + wsum[1]) + (wsum[2] + wsum[3]);
    atomicAdd(loss_out, blk * LOSS_SCALE);
  }
}

extern "C" void kernel_launch(void* const* d_in, const int* in_sizes, int n_in,
                              void* d_out, int out_size, void* d_ws, size_t ws_size,
                              hipStream_t stream) {
  const float* lat  = (const float*)d_in[0];
  const float* cent = (const float*)d_in[1];
  const float* lf   = (const float*)d_in[2];
  float* out = (float*)d_out;
  unsigned short* centbf = (unsigned short*)d_ws;                 // 64 KB
  float4* cnormb4 = (float4*)((char*)d_ws + 65536);               // 16 KB
  float* loss = out + TOTAL_ELEMS;

  prep_kernel<<<K * D / 8 / 256, 256, 0, stream>>>(cent, centbf, cnormb4, loss);
  vq_kernel<<<N_ROWS / 256, 256, 0, stream>>>(lat, centbf, cnormb4, lf,
                                              out, loss);
}